// Round 1
// baseline (742.795 us; speedup 1.0000x reference)
//
#include <hip/hip_runtime.h>
#include <hip/hip_bf16.h>

// Scatter-mean pooling: x (N=1048576, D=128) fp32, batch sorted int32 (N,),
// out (num_graphs=4096, D=128) fp32.
//
// Strategy (memory-bound, ~518 MiB must move):
//  - batch is SORTED -> segments are contiguous runs (avg N/B = 256 rows).
//  - Kernel 1: each block owns a 512-row chunk. 256 threads: thread t handles
//    float4-column (t & 31) of rows (t >> 5) + 8*i. Accumulate in registers
//    while segment id is constant; atomicAdd to out only at run boundaries.
//    ~6M atomics total over 524K addresses -> negligible contention.
//  - Kernel 2: per-segment count via binary search on sorted batch (20 steps,
//    L2-resident 4 MiB array), then divide. Empty segments stay 0 (match ref).
//  - d_out poisoned with 0xAA each call -> hipMemsetAsync zero-init first.

#define D       128
#define D4      32      // float4 per row
#define RPB     512     // rows per block (kernel 1)
#define THREADS 256
#define RIF     8       // rows in flight = THREADS / D4

__global__ __launch_bounds__(THREADS)
void pool_sum_kernel(const float4* __restrict__ x,
                     const int* __restrict__ batch,
                     float* __restrict__ out,
                     int n_rows) {
    __shared__ int sbatch[RPB];
    const int base = blockIdx.x * RPB;
    const int tid  = threadIdx.x;

    // Stage this chunk's segment ids in LDS (coalesced, read many times).
    for (int i = tid; i < RPB; i += THREADS) {
        int r = base + i;
        sbatch[i] = (r < n_rows) ? batch[r] : -1;
    }
    __syncthreads();

    const int col = tid & (D4 - 1);   // float4 column 0..31
    const int rl  = tid >> 5;         // row lane 0..7

    float4 acc = make_float4(0.f, 0.f, 0.f, 0.f);
    int cur = -1;

    for (int i = rl; i < RPB; i += RIF) {
        int r = base + i;
        if (r >= n_rows) break;
        int seg = sbatch[i];
        float4 v = x[(size_t)r * D4 + col];
        if (seg != cur) {
            if (cur >= 0) {
                float* o = out + (size_t)cur * D + col * 4;
                atomicAdd(o + 0, acc.x);
                atomicAdd(o + 1, acc.y);
                atomicAdd(o + 2, acc.z);
                atomicAdd(o + 3, acc.w);
            }
            cur = seg;
            acc = make_float4(0.f, 0.f, 0.f, 0.f);
        }
        acc.x += v.x; acc.y += v.y; acc.z += v.z; acc.w += v.w;
    }
    if (cur >= 0) {
        float* o = out + (size_t)cur * D + col * 4;
        atomicAdd(o + 0, acc.x);
        atomicAdd(o + 1, acc.y);
        atomicAdd(o + 2, acc.z);
        atomicAdd(o + 3, acc.w);
    }
}

__device__ __forceinline__ int lower_bound_dev(const int* __restrict__ a,
                                               int n, int v) {
    int lo = 0, hi = n;
    while (lo < hi) {
        int mid = (lo + hi) >> 1;
        if (a[mid] < v) lo = mid + 1; else hi = mid;
    }
    return lo;
}

__global__ __launch_bounds__(D)
void pool_div_kernel(float* __restrict__ out,
                     const int* __restrict__ batch,
                     int n_rows) {
    const int s = blockIdx.x;
    __shared__ float cnt_s;
    if (threadIdx.x == 0) {
        int lo = lower_bound_dev(batch, n_rows, s);
        int hi = lower_bound_dev(batch, n_rows, s + 1);
        int cnt = hi - lo;
        cnt_s = (float)(cnt > 1 ? cnt : 1);
    }
    __syncthreads();
    size_t idx = (size_t)s * D + threadIdx.x;
    out[idx] = out[idx] / cnt_s;
}

extern "C" void kernel_launch(void* const* d_in, const int* in_sizes, int n_in,
                              void* d_out, int out_size, void* d_ws, size_t ws_size,
                              hipStream_t stream) {
    const float4* x   = (const float4*)d_in[0];
    const int* batch  = (const int*)d_in[1];
    float* out        = (float*)d_out;

    const int n_rows     = in_sizes[0] / D;   // 1048576
    const int num_graphs = out_size / D;      // 4096

    // d_out is poisoned (0xAA) before every call: zero it (graph-capturable).
    hipMemsetAsync(d_out, 0, (size_t)out_size * sizeof(float), stream);

    int blocks = (n_rows + RPB - 1) / RPB;    // 2048
    pool_sum_kernel<<<blocks, THREADS, 0, stream>>>(x, batch, out, n_rows);
    pool_div_kernel<<<num_graphs, D, 0, stream>>>(out, batch, n_rows);
}

// Round 2
// 712.280 us; speedup vs baseline: 1.0428x; 1.0428x over previous
//
#include <hip/hip_runtime.h>
#include <hip/hip_bf16.h>

// Scatter-mean pooling: x (N=1048576, D=128) fp32, batch sorted int32 (N,),
// out (num_graphs=4096, D=128) fp32.
//
// Memory-bound: must stream 512 MiB of x once -> ~85-90 us floor at 6.3 TB/s.
// R1 change: 4-deep load pipeline (4 independent nontemporal float4 loads in
// flight per wave) instead of 1 load + branchy consume per iteration, which
// serialized on s_waitcnt vmcnt(0). Full-chunk fast path removes bounds checks.

#define D       128
#define D4      32      // float4 per row
#define RPB     512     // rows per block (kernel 1)
#define THREADS 256
#define RIF     8       // rows in flight per pass = THREADS / D4
#define UNROLL  4

typedef float v4f __attribute__((ext_vector_type(4)));

__device__ __forceinline__ void flush_acc(float* __restrict__ out,
                                          int seg, int col, const v4f& acc) {
    float* o = out + (size_t)seg * D + col * 4;
    atomicAdd(o + 0, acc.x);
    atomicAdd(o + 1, acc.y);
    atomicAdd(o + 2, acc.z);
    atomicAdd(o + 3, acc.w);
}

__device__ __forceinline__ void step_row(const int* __restrict__ sbatch, int i,
                                         v4f v, int col,
                                         float* __restrict__ out,
                                         int& cur, v4f& acc) {
    int seg = sbatch[i];
    if (seg != cur) {
        if (cur >= 0) flush_acc(out, cur, col, acc);
        cur = seg;
        acc = (v4f){0.f, 0.f, 0.f, 0.f};
    }
    acc += v;
}

__global__ __launch_bounds__(THREADS)
void pool_sum_kernel(const v4f* __restrict__ x,
                     const int* __restrict__ batch,
                     float* __restrict__ out,
                     int n_rows) {
    __shared__ int sbatch[RPB];
    const int base = blockIdx.x * RPB;
    const int tid  = threadIdx.x;

    for (int i = tid; i < RPB; i += THREADS) {
        int r = base + i;
        sbatch[i] = (r < n_rows) ? batch[r] : -1;
    }
    __syncthreads();

    const int col = tid & (D4 - 1);   // float4 column 0..31
    const int rl  = tid >> 5;         // row lane 0..7

    v4f acc = (v4f){0.f, 0.f, 0.f, 0.f};
    int cur = -1;

    const int nloc = n_rows - base;   // rows available in this chunk

    if (nloc >= RPB) {
        // Full chunk: no bounds checks, 4 independent loads in flight.
        const v4f* p = x + (size_t)(base + rl) * D4 + col;
        for (int i = rl; i < RPB; i += UNROLL * RIF) {
            v4f v0 = __builtin_nontemporal_load(p + 0 * RIF * D4);
            v4f v1 = __builtin_nontemporal_load(p + 1 * RIF * D4);
            v4f v2 = __builtin_nontemporal_load(p + 2 * RIF * D4);
            v4f v3 = __builtin_nontemporal_load(p + 3 * RIF * D4);
            step_row(sbatch, i + 0 * RIF, v0, col, out, cur, acc);
            step_row(sbatch, i + 1 * RIF, v1, col, out, cur, acc);
            step_row(sbatch, i + 2 * RIF, v2, col, out, cur, acc);
            step_row(sbatch, i + 3 * RIF, v3, col, out, cur, acc);
            p += UNROLL * RIF * D4;
        }
    } else {
        // Tail chunk (not hit at N=1M, RPB=512, but keep correct).
        for (int i = rl; i < nloc; i += RIF) {
            v4f v = __builtin_nontemporal_load(x + (size_t)(base + i) * D4 + col);
            step_row(sbatch, i, v, col, out, cur, acc);
        }
    }
    if (cur >= 0) flush_acc(out, cur, col, acc);
}

__device__ __forceinline__ int lower_bound_dev(const int* __restrict__ a,
                                               int n, int v) {
    int lo = 0, hi = n;
    while (lo < hi) {
        int mid = (lo + hi) >> 1;
        if (a[mid] < v) lo = mid + 1; else hi = mid;
    }
    return lo;
}

__global__ __launch_bounds__(D)
void pool_div_kernel(float* __restrict__ out,
                     const int* __restrict__ batch,
                     int n_rows) {
    const int s = blockIdx.x;
    __shared__ float cnt_s;
    if (threadIdx.x == 0) {
        int lo = lower_bound_dev(batch, n_rows, s);
        int hi = lower_bound_dev(batch, n_rows, s + 1);
        int cnt = hi - lo;
        cnt_s = (float)(cnt > 1 ? cnt : 1);
    }
    __syncthreads();
    size_t idx = (size_t)s * D + threadIdx.x;
    out[idx] = out[idx] / cnt_s;
}

extern "C" void kernel_launch(void* const* d_in, const int* in_sizes, int n_in,
                              void* d_out, int out_size, void* d_ws, size_t ws_size,
                              hipStream_t stream) {
    const v4f* x      = (const v4f*)d_in[0];
    const int* batch  = (const int*)d_in[1];
    float* out        = (float*)d_out;

    const int n_rows     = in_sizes[0] / D;   // 1048576
    const int num_graphs = out_size / D;      // 4096

    // d_out is poisoned (0xAA) before every call: zero it (graph-capturable).
    hipMemsetAsync(d_out, 0, (size_t)out_size * sizeof(float), stream);

    int blocks = (n_rows + RPB - 1) / RPB;    // 2048
    pool_sum_kernel<<<blocks, THREADS, 0, stream>>>(x, batch, out, n_rows);
    pool_div_kernel<<<num_graphs, D, 0, stream>>>(out, batch, n_rows);
}

// Round 3
// 656.465 us; speedup vs baseline: 1.1315x; 1.0850x over previous
//
#include <hip/hip_runtime.h>
#include <hip/hip_bf16.h>

// Scatter-mean pooling: x (N=1048576, D=128) fp32, batch sorted int32 (N,),
// out (num_graphs=4096, D=128) fp32.
//
// R2 structure: ONE BLOCK PER SEGMENT. batch is sorted, so segment s is the
// contiguous row range [lower_bound(s), lower_bound(s+1)). Each block:
//   1. binary-searches its run bounds (batch is 4 MiB, L2-resident; ~40
//      same-address broadcast loads per block),
//   2. streams its ~256 rows with a 4-deep nontemporal float4 pipeline
//      (thread t: col t&31, row-lane t>>5 -> 8 rows in flight per pass),
//   3. LDS-reduces the 8 row-lane partials, scales by 1/max(cnt,1),
//   4. writes its 512 B of out exactly once.
// Eliminates ALL atomics, the d_out memset, and the second kernel. Empty
// segments write zeros (acc=0, cnt clamped to 1) matching the reference.

#define D       128
#define D4      32      // float4 per row
#define THREADS 256
#define RIF     8       // rows in flight per pass = THREADS / D4
#define UNROLL  4

typedef float v4f __attribute__((ext_vector_type(4)));

__device__ __forceinline__ int lower_bound_dev(const int* __restrict__ a,
                                               int lo, int hi, int v) {
    while (lo < hi) {
        int mid = (lo + hi) >> 1;
        if (a[mid] < v) lo = mid + 1; else hi = mid;
    }
    return lo;
}

__global__ __launch_bounds__(THREADS)
void pool_mean_kernel(const v4f* __restrict__ x,
                      const int* __restrict__ batch,
                      float* __restrict__ out,
                      int n_rows) {
    const int s = blockIdx.x;

    // Run bounds for segment s. All threads compute redundantly (same
    // addresses -> L1 broadcast); avoids an LDS round-trip + barrier.
    const int lo = lower_bound_dev(batch, 0, n_rows, s);
    const int hi = lower_bound_dev(batch, lo, n_rows, s + 1);
    const int cnt = hi - lo;
    const float inv = 1.0f / (float)(cnt > 1 ? cnt : 1);

    const int col = threadIdx.x & (D4 - 1);   // float4 column 0..31
    const int rl  = threadIdx.x >> 5;         // row lane 0..7

    v4f acc = (v4f){0.f, 0.f, 0.f, 0.f};

    // 4-deep software pipeline over this thread's rows (lo+rl, step 8).
    int i = lo + rl;
    const v4f* p = x + (size_t)i * D4 + col;
    for (; i + (UNROLL - 1) * RIF < hi; i += UNROLL * RIF) {
        v4f v0 = __builtin_nontemporal_load(p + 0 * RIF * D4);
        v4f v1 = __builtin_nontemporal_load(p + 1 * RIF * D4);
        v4f v2 = __builtin_nontemporal_load(p + 2 * RIF * D4);
        v4f v3 = __builtin_nontemporal_load(p + 3 * RIF * D4);
        acc += v0; acc += v1; acc += v2; acc += v3;
        p += UNROLL * RIF * D4;
    }
    for (; i < hi; i += RIF) {
        acc += __builtin_nontemporal_load(p);
        p += RIF * D4;
    }

    // Reduce 8 row-lanes -> 1 via LDS.
    __shared__ v4f partials[RIF][D4];
    partials[rl][col] = acc;
    __syncthreads();

    if (threadIdx.x < D4) {
        v4f t = partials[0][col];
        #pragma unroll
        for (int r = 1; r < RIF; ++r) t += partials[r][col];
        t *= inv;
        v4f* o = (v4f*)out + (size_t)s * D4 + col;
        __builtin_nontemporal_store(t, o);
    }
}

extern "C" void kernel_launch(void* const* d_in, const int* in_sizes, int n_in,
                              void* d_out, int out_size, void* d_ws, size_t ws_size,
                              hipStream_t stream) {
    const v4f* x      = (const v4f*)d_in[0];
    const int* batch  = (const int*)d_in[1];
    float* out        = (float*)d_out;

    const int n_rows     = in_sizes[0] / D;   // 1048576
    const int num_graphs = out_size / D;      // 4096

    // Every out element is written by its owning block -> no memset needed.
    pool_mean_kernel<<<num_graphs, THREADS, 0, stream>>>(x, batch, out, n_rows);
}

// Round 4
// 648.542 us; speedup vs baseline: 1.1453x; 1.0122x over previous
//
#include <hip/hip_runtime.h>
#include <hip/hip_bf16.h>

// Scatter-mean pooling: x (N=1048576, D=128) fp32, batch sorted int32 (N,),
// out (num_graphs=4096, D=128) fp32.
//
// R3 structure:
//  Kernel A (find_starts): thread i compares batch[i] vs batch[i-1]; at each
//    run boundary writes starts[] (in d_ws). Covers s=0, empty segments, and
//    the tail, so every starts[0..num_graphs] entry is written exactly once.
//    ~4-8 MiB of reads (~2 us) -- replaces the per-block 40-step DEPENDENT
//    binary-search chain (~5-8 us un-overlappable prologue in the R2 kernel).
//  Kernel B (pool_mean): one block per segment; bounds via two broadcast
//    loads of starts[]; streams its ~256 rows with an 8-deep nontemporal
//    float4 pipeline; LDS-reduces 8 row-lanes; scales by 1/max(cnt,1);
//    writes its 512 B of out exactly once. No atomics, no memset.

#define D       128
#define D4      32      // float4 per row
#define THREADS 256
#define RIF     8       // rows in flight per pass = THREADS / D4
#define UNROLL  8

typedef float v4f __attribute__((ext_vector_type(4)));

__global__ __launch_bounds__(256)
void find_starts_kernel(const int* __restrict__ batch,
                        int* __restrict__ starts,
                        int n_rows, int num_graphs) {
    int i = blockIdx.x * blockDim.x + threadIdx.x;
    if (i >= n_rows) return;
    int b    = batch[i];
    int prev = (i == 0) ? -1 : batch[i - 1];
    for (int s = prev + 1; s <= b; ++s) starts[s] = i;       // run starts
    if (i == n_rows - 1) {
        for (int s = b + 1; s <= num_graphs; ++s) starts[s] = n_rows; // tail
    }
}

__global__ __launch_bounds__(THREADS)
void pool_mean_kernel(const v4f* __restrict__ x,
                      const int* __restrict__ starts,
                      float* __restrict__ out) {
    const int s = blockIdx.x;

    // Two same-address broadcast loads (L2-hot 16 KiB array) -- no chain.
    const int lo  = starts[s];
    const int hi  = starts[s + 1];
    const int cnt = hi - lo;
    const float inv = 1.0f / (float)(cnt > 1 ? cnt : 1);

    const int col = threadIdx.x & (D4 - 1);   // float4 column 0..31
    const int rl  = threadIdx.x >> 5;         // row lane 0..7

    v4f acc = (v4f){0.f, 0.f, 0.f, 0.f};

    // 8-deep software pipeline over this thread's rows (lo+rl, step 8).
    int i = lo + rl;
    const v4f* p = x + (size_t)i * D4 + col;
    for (; i + (UNROLL - 1) * RIF < hi; i += UNROLL * RIF) {
        v4f v0 = __builtin_nontemporal_load(p + 0 * RIF * D4);
        v4f v1 = __builtin_nontemporal_load(p + 1 * RIF * D4);
        v4f v2 = __builtin_nontemporal_load(p + 2 * RIF * D4);
        v4f v3 = __builtin_nontemporal_load(p + 3 * RIF * D4);
        v4f v4 = __builtin_nontemporal_load(p + 4 * RIF * D4);
        v4f v5 = __builtin_nontemporal_load(p + 5 * RIF * D4);
        v4f v6 = __builtin_nontemporal_load(p + 6 * RIF * D4);
        v4f v7 = __builtin_nontemporal_load(p + 7 * RIF * D4);
        acc += v0; acc += v1; acc += v2; acc += v3;
        acc += v4; acc += v5; acc += v6; acc += v7;
        p += UNROLL * RIF * D4;
    }
    for (; i < hi; i += RIF) {
        acc += __builtin_nontemporal_load(p);
        p += RIF * D4;
    }

    // Reduce 8 row-lanes -> 1 via LDS.
    __shared__ v4f partials[RIF][D4];
    partials[rl][col] = acc;
    __syncthreads();

    if (threadIdx.x < D4) {
        v4f t = partials[0][col];
        #pragma unroll
        for (int r = 1; r < RIF; ++r) t += partials[r][col];
        t *= inv;
        v4f* o = (v4f*)out + (size_t)s * D4 + col;
        __builtin_nontemporal_store(t, o);
    }
}

extern "C" void kernel_launch(void* const* d_in, const int* in_sizes, int n_in,
                              void* d_out, int out_size, void* d_ws, size_t ws_size,
                              hipStream_t stream) {
    const v4f* x      = (const v4f*)d_in[0];
    const int* batch  = (const int*)d_in[1];
    float* out        = (float*)d_out;
    int* starts       = (int*)d_ws;           // (num_graphs+1) ints

    const int n_rows     = in_sizes[0] / D;   // 1048576
    const int num_graphs = out_size / D;      // 4096

    find_starts_kernel<<<(n_rows + 255) / 256, 256, 0, stream>>>(
        batch, starts, n_rows, num_graphs);
    pool_mean_kernel<<<num_graphs, THREADS, 0, stream>>>(x, starts, out);
}